// Round 4
// baseline (50.893 us; speedup 1.0000x reference)
//
#include <hip/hip_runtime.h>
#include <math.h>

#define NCLS 81
#define KMAX 200
#define NMAX 1536      // max candidates per (b,l) stageable in LDS (>= N=1500)
#define SORT_CAP 2048  // >= max total detections per batch (<= N)

// ws layout (all offsets 16B-aligned):
//   counts   [B*NCLS] int      @ 0        (4 KB region)
//   entries  [B*NCLS][KMAX][8] @ 4096     (2 073 600 B)
//   cand_cls [B*N] int         @ 2077696
//   cand_sc  [B*N] float       @ +24064
//   cand_box [B*N] float4      @ +24064

// ---------------------------------------------------------------------------
// K1: one wave per 64 rows. Coalesced-stage 64 probs rows into LDS, per-lane
// row max/argmax (prob>0.7 => unique strict argmax => candidate class), decode
// the candidate's box, write dense candidate arrays. No atomics.
// ---------------------------------------------------------------------------
__global__ __launch_bounds__(64) void row_scan(
    const float* __restrict__ rois,     // [B*N,4]
    const float* __restrict__ deltas,   // [B*N,81*4]
    const float* __restrict__ probs,    // [B*N,81]
    int* __restrict__ cand_cls,         // [B*N]
    float* __restrict__ cand_sc,        // [B*N]
    float4* __restrict__ cand_box,      // [B*N]
    int BN) {
  __shared__ float s_p[64 * NCLS];
  const int lane = threadIdx.x;
  const int row0 = blockIdx.x * 64;
  const int nrows = min(64, BN - row0);

  const float* src = probs + (size_t)row0 * NCLS;
  const int tot = nrows * NCLS;
  for (int i = lane; i < tot; i += 64) s_p[i] = src[i];
  __syncthreads();
  if (lane >= nrows) return;

  const int row = row0 + lane;
  const float* pr = s_p + lane * NCLS;   // stride-81 across lanes: 2-way alias, free
  float maxv = pr[0];
  int arg = 0;
  for (int k = 1; k < NCLS; ++k) {
    const float v = pr[k];
    if (v > maxv) { maxv = v; arg = k; }   // strict > keeps lowest index (jnp.argmax)
  }
  const bool cand = (maxv > 0.7f) && (arg != 0);
  cand_cls[row] = cand ? arg : -1;
  cand_sc[row] = maxv;
  if (cand) {
    const float* r = rois + (size_t)row * 4;
    const float ay1 = r[0], ax1 = r[1], ay2 = r[2], ax2 = r[3];
    const float h = ay2 - ay1, w = ax2 - ax1;
    const float cy = ay1 + 0.5f * h, cx = ax1 + 0.5f * w;
    const float* d = deltas + (size_t)row * (NCLS * 4) + arg * 4;
    const float bh  = expf(d[2] * 0.2f) * h;
    const float bw  = expf(d[3] * 0.2f) * w;
    const float bcy = d[0] * 0.1f * h + cy;
    const float bcx = d[1] * 0.1f * w + cx;
    const float y1 = bcy - 0.5f * bh, x1 = bcx - 0.5f * bw;
    cand_box[row] = make_float4(y1, x1, y1 + bh, x1 + bw);  // unclipped for NMS
  }
}

// ---------------------------------------------------------------------------
// K2: one wave per (b,l). Compact this class's candidates (coalesced int scan
// of cand_cls, n-ascending order preserved), exact greedy NMS (equivalent to
// the reference's 200-step scan), write per-class entries + count. No atomics.
// ---------------------------------------------------------------------------
__global__ __launch_bounds__(64) void nms_per_class(
    const int* __restrict__ cand_cls,   // [B*N]
    const float* __restrict__ cand_sc,  // [B*N]
    const float4* __restrict__ cand_box,// [B*N]
    float* __restrict__ entries,        // [B*NCLS][KMAX][8]
    int* __restrict__ counts,           // [B*NCLS]
    int N) {
  const int bl = blockIdx.x;
  const int b  = bl / NCLS;
  const int l  = bl % NCLS;
  const int lane = threadIdx.x;
  if (l == 0) {                 // background never passes the threshold
    if (lane == 0) counts[bl] = 0;
    return;
  }

  __shared__ float s_score[NMAX];
  __shared__ float s_box[NMAX][4];
  __shared__ int   s_sel[KMAX];
  __shared__ float s_sel_score[KMAX];

  // ---- candidate compaction (coalesced; n-ascending order preserved) ----
  int m = 0;
  for (int n0 = 0; n0 < N; n0 += 64) {
    const int n = n0 + lane;
    const int c = (n < N) ? cand_cls[b * N + n] : -1;
    const bool cand = (c == l);
    const unsigned long long mask = __ballot(cand);
    if (cand) {
      const int idx = m + __popcll(mask & ((1ull << lane) - 1ull));
      const float4 bx = cand_box[b * N + n];
      s_score[idx]  = cand_sc[b * N + n];
      s_box[idx][0] = bx.x;
      s_box[idx][1] = bx.y;
      s_box[idx][2] = bx.z;
      s_box[idx][3] = bx.w;
    }
    m += __popcll(mask);
  }
  __syncthreads();

  // ---- greedy NMS ----
  int kept = 0;
  while (kept < KMAX) {
    float best = -1.0f;
    int bi = -1;
    for (int i = lane; i < m; i += 64) {
      const float s = s_score[i];
      if (s > best) { best = s; bi = i; }   // strided ascending: first max kept
    }
    for (int off = 32; off > 0; off >>= 1) {
      const float ob = __shfl_down(best, off);
      const int   oi = __shfl_down(bi, off);
      if (ob > best || (ob == best && (unsigned)oi < (unsigned)bi)) {
        best = ob; bi = oi;
      }
    }
    best = __shfl(best, 0);
    bi   = __shfl(bi, 0);
    if (best <= 0.7f) break;   // all remaining picks invalid

    if (lane == 0) { s_sel[kept] = bi; s_sel_score[kept] = best; }

    const float by1 = s_box[bi][0], bx1 = s_box[bi][1];
    const float by2 = s_box[bi][2], bx2 = s_box[bi][3];
    const float a1 = (by2 - by1) * (bx2 - bx1);
    for (int i = lane; i < m; i += 64) {
      const float ty1 = s_box[i][0], tx1 = s_box[i][1];
      const float ty2 = s_box[i][2], tx2 = s_box[i][3];
      const float yy1 = fmaxf(by1, ty1), xx1 = fmaxf(bx1, tx1);
      const float yy2 = fminf(by2, ty2), xx2 = fminf(bx2, tx2);
      const float inter = fmaxf(yy2 - yy1, 0.0f) * fmaxf(xx2 - xx1, 0.0f);
      const float a2  = (ty2 - ty1) * (tx2 - tx1);
      const float uni = a1 + a2 - inter;
      const float iou = (uni > 0.0f) ? (inter / uni) : 0.0f;
      if (iou > 0.5f) s_score[i] = -INFINITY;   // self iou=1 -> suppressed
    }
    kept++;
    __syncthreads();
  }
  __syncthreads();

  // ---- write per-class results ----
  if (lane == 0) counts[bl] = kept;
  float* ebase = entries + (size_t)bl * KMAX * 8;
  for (int i = lane; i < kept; i += 64) {
    float* e = ebase + (size_t)i * 8;
    const int ci = s_sel[i];
    e[0] = s_sel_score[i];
    e[1] = fminf(fmaxf(s_box[ci][0], 0.0f), 1.0f);
    e[2] = fminf(fmaxf(s_box[ci][1], 0.0f), 1.0f);
    e[3] = fminf(fmaxf(s_box[ci][2], 0.0f), 1.0f);
    e[4] = fminf(fmaxf(s_box[ci][3], 0.0f), 1.0f);
  }
}

// ---------------------------------------------------------------------------
// K3: one block per batch. Prefix-sum the 81 counts, gather 64-bit keys
// (score desc, flat index asc — low bits ARE the payload), bitonic sort only
// next_pow2(total) slots, emit top-200.
// ---------------------------------------------------------------------------
__global__ __launch_bounds__(1024) void topk_per_batch(
    const float* __restrict__ entries,  // [B*NCLS][KMAX][8]
    const int* __restrict__ counts,     // [B*NCLS]
    float* __restrict__ out, int B) {
  const int b   = blockIdx.x;
  const int tid = threadIdx.x;

  __shared__ int s_cnt[NCLS];
  __shared__ int s_off[NCLS];
  __shared__ int s_total, s_M;
  __shared__ unsigned long long s_key[SORT_CAP];

  if (tid < NCLS) s_cnt[tid] = counts[b * NCLS + tid];
  __syncthreads();
  if (tid == 0) {
    int acc = 0;
    for (int l = 0; l < NCLS; ++l) { s_off[l] = acc; acc += s_cnt[l]; }
    s_total = acc;
    int M = 64;
    while (M < acc) M <<= 1;
    s_M = M;
  }
  __syncthreads();
  const int c = s_total;
  const int M = s_M;     // c <= N <= SORT_CAP guaranteed

  for (int i = tid; i < M; i += 1024) s_key[i] = 0ull;
  __syncthreads();
  for (int j = tid; j < NCLS * KMAX; j += 1024) {
    const int l = j / KMAX, k = j - l * KMAX;
    if (k < s_cnt[l]) {
      const float sc = entries[((size_t)(b * NCLS + l) * KMAX + k) * 8];
      const unsigned sb = __float_as_uint(sc);           // score > 0.7 > 0
      s_key[s_off[l] + k] =
          ((unsigned long long)sb << 32) |
          (unsigned long long)(0xFFFFFFFFu - (unsigned)(l * KMAX + k));
    }
  }
  __syncthreads();

  for (int kk = 2; kk <= M; kk <<= 1) {
    for (int j2 = kk >> 1; j2 > 0; j2 >>= 1) {
      for (int i = tid; i < M; i += 1024) {
        const int ixj = i ^ j2;
        if (ixj > i) {
          const bool up = ((i & kk) == 0);  // descending overall
          const unsigned long long a = s_key[i], bb = s_key[ixj];
          const bool sw = up ? (a < bb) : (a > bb);
          if (sw) { s_key[i] = bb; s_key[ixj] = a; }
        }
      }
      __syncthreads();
    }
  }

  if (tid < KMAX) {
    float sc = 0.0f, lb = 0.0f, b0 = 0.0f, b1 = 0.0f, b2 = 0.0f, b3 = 0.0f;
    if (tid < c) {
      const unsigned long long k = s_key[tid];
      const unsigned fi = 0xFFFFFFFFu - (unsigned)(k & 0xFFFFFFFFull);
      const int l = fi / KMAX, kk2 = fi - l * KMAX;
      const float* e = entries + ((size_t)(b * NCLS + l) * KMAX + kk2) * 8;
      sc = e[0];
      lb = (float)l;
      b0 = e[1]; b1 = e[2]; b2 = e[3]; b3 = e[4];
    }
    float* ob = out + (size_t)b * (KMAX * 4) + (size_t)tid * 4;
    ob[0] = b0; ob[1] = b1; ob[2] = b2; ob[3] = b3;
    const size_t boxes_sz = (size_t)B * KMAX * 4;
    out[boxes_sz + (size_t)b * KMAX + tid] = lb;
    out[boxes_sz + (size_t)B * KMAX + (size_t)b * KMAX + tid] = sc;
  }
}

// ---------------------------------------------------------------------------
extern "C" void kernel_launch(void* const* d_in, const int* in_sizes, int n_in,
                              void* d_out, int out_size, void* d_ws, size_t ws_size,
                              hipStream_t stream) {
  const float* rois   = (const float*)d_in[0];
  const float* deltas = (const float*)d_in[1];
  const float* probs  = (const float*)d_in[2];
  float* out = (float*)d_out;

  const int B = 4;
  const int N = in_sizes[0] / (B * 4);   // 1500
  const int BN = B * N;

  char* ws = (char*)d_ws;
  int*    counts   = (int*)ws;
  float*  entries  = (float*)(ws + 4096);
  int*    cand_cls = (int*)(ws + 2077696);
  float*  cand_sc  = (float*)(ws + 2077696 + 24064);
  float4* cand_box = (float4*)(ws + 2077696 + 24064 + 24064);

  hipLaunchKernelGGL(row_scan, dim3((BN + 63) / 64), dim3(64), 0, stream,
                     rois, deltas, probs, cand_cls, cand_sc, cand_box, BN);
  hipLaunchKernelGGL(nms_per_class, dim3(B * NCLS), dim3(64), 0, stream,
                     cand_cls, cand_sc, cand_box, entries, counts, N);
  hipLaunchKernelGGL(topk_per_batch, dim3(B), dim3(1024), 0, stream,
                     entries, counts, out, B);
}

// Round 5
// 45.291 us; speedup vs baseline: 1.1237x; 1.1237x over previous
//
#include <hip/hip_runtime.h>
#include <math.h>

#define NCLS 81
#define KMAX 200
#define NMAX 1536      // max candidates per (b,l) stageable in LDS (>= N=1500)
#define SORT_CAP 2048  // >= max total detections per batch (<= N)

// ws layout:
//   counts   [B*NCLS] int      @ 0
//   entries  [B*NCLS][KMAX][8] @ 4096
//   cand_cls [B*N] int         @ 2077696
//   cand_sc  [B*N] float       @ +24064
//   cand_box [B*N] float4      @ +24064

// ---------------------------------------------------------------------------
// K1: one wave per 64 rows. Stage 64 probs rows into LDS with UNROLLED float4
// loads (all in flight -> ~1 latency round), per-lane 81-wide argmax
// (prob>0.7 => unique strict argmax), decode candidate box, dense outputs.
// ---------------------------------------------------------------------------
__global__ __launch_bounds__(64) void row_scan(
    const float* __restrict__ rois,     // [B*N,4]
    const float* __restrict__ deltas,   // [B*N,81*4]
    const float* __restrict__ probs,    // [B*N,81]
    int* __restrict__ cand_cls,         // [B*N]
    float* __restrict__ cand_sc,        // [B*N]
    float4* __restrict__ cand_box,      // [B*N]
    int BN) {
  __shared__ float s_p[64 * NCLS];
  const int lane = threadIdx.x;
  const int row0 = blockIdx.x * 64;

  if (row0 + 64 <= BN) {
    // 64*81 = 5184 floats = 1296 float4; base is 16B-aligned (row0*324 % 16 == 0)
    const float4* src4 = (const float4*)(probs + (size_t)row0 * NCLS);
    float4* dst4 = (float4*)s_p;
#pragma unroll
    for (int it = 0; it < 21; ++it) {
      const int idx = it * 64 + lane;
      if (idx < 1296) dst4[idx] = src4[idx];
    }
  } else {
    const int tot = (BN - row0) * NCLS;
    const float* src = probs + (size_t)row0 * NCLS;
    for (int i = lane; i < tot; i += 64) s_p[i] = src[i];
  }
  __syncthreads();

  const int row = row0 + lane;
  if (row >= BN) return;
  const float* pr = s_p + lane * NCLS;  // stride-81: 2-way bank alias, free
  float maxv = pr[0];
  int arg = 0;
#pragma unroll
  for (int k = 1; k < NCLS; ++k) {
    const float v = pr[k];
    if (v > maxv) { maxv = v; arg = k; }  // strict > keeps lowest idx (jnp.argmax)
  }
  const bool cand = (maxv > 0.7f) && (arg != 0);
  cand_cls[row] = cand ? arg : -1;
  cand_sc[row] = maxv;
  if (cand) {
    const float* r = rois + (size_t)row * 4;
    const float ay1 = r[0], ax1 = r[1], ay2 = r[2], ax2 = r[3];
    const float h = ay2 - ay1, w = ax2 - ax1;
    const float cy = ay1 + 0.5f * h, cx = ax1 + 0.5f * w;
    const float* d = deltas + (size_t)row * (NCLS * 4) + arg * 4;
    const float bh  = expf(d[2] * 0.2f) * h;
    const float bw  = expf(d[3] * 0.2f) * w;
    const float bcy = d[0] * 0.1f * h + cy;
    const float bcx = d[1] * 0.1f * w + cx;
    const float y1 = bcy - 0.5f * bh, x1 = bcx - 0.5f * bw;
    cand_box[row] = make_float4(y1, x1, y1 + bh, x1 + bw);  // unclipped for NMS
  }
}

// ---------------------------------------------------------------------------
// K2 core: compaction records row indices only (n-ascending); ONE cooperative
// gather pass fills score+box (single latency round); exact greedy NMS
// (equivalent to the reference's 200-step scan); per-class output, no atomics.
// ---------------------------------------------------------------------------
__device__ __forceinline__ void nms_body(
    const float* __restrict__ cand_sc, const float4* __restrict__ cand_box,
    float* __restrict__ entries, int* __restrict__ counts,
    int N, int b, int l, int bl, int lane, int m,
    int* s_idx, float* s_score, float (*s_box)[4],
    int* s_sel, float* s_sel_score) {
  // cooperative gather: all candidate loads issued in parallel
  for (int i = lane; i < m; i += 64) {
    const int n = s_idx[i];
    s_score[i] = cand_sc[b * N + n];
    const float4 bx = cand_box[b * N + n];
    s_box[i][0] = bx.x; s_box[i][1] = bx.y;
    s_box[i][2] = bx.z; s_box[i][3] = bx.w;
  }
  __syncthreads();

  int kept = 0;
  while (kept < KMAX) {
    float best = -1.0f;
    int bi = -1;
    for (int i = lane; i < m; i += 64) {
      const float s = s_score[i];
      if (s > best) { best = s; bi = i; }   // strided ascending: first max kept
    }
    for (int off = 32; off > 0; off >>= 1) {
      const float ob = __shfl_down(best, off);
      const int   oi = __shfl_down(bi, off);
      if (ob > best || (ob == best && (unsigned)oi < (unsigned)bi)) {
        best = ob; bi = oi;
      }
    }
    best = __shfl(best, 0);
    bi   = __shfl(bi, 0);
    if (best <= 0.7f) break;   // all remaining picks invalid

    if (lane == 0) { s_sel[kept] = bi; s_sel_score[kept] = best; }

    const float by1 = s_box[bi][0], bx1 = s_box[bi][1];
    const float by2 = s_box[bi][2], bx2 = s_box[bi][3];
    const float a1 = (by2 - by1) * (bx2 - bx1);
    for (int i = lane; i < m; i += 64) {
      const float ty1 = s_box[i][0], tx1 = s_box[i][1];
      const float ty2 = s_box[i][2], tx2 = s_box[i][3];
      const float yy1 = fmaxf(by1, ty1), xx1 = fmaxf(bx1, tx1);
      const float yy2 = fminf(by2, ty2), xx2 = fminf(bx2, tx2);
      const float inter = fmaxf(yy2 - yy1, 0.0f) * fmaxf(xx2 - xx1, 0.0f);
      const float a2  = (ty2 - ty1) * (tx2 - tx1);
      const float uni = a1 + a2 - inter;
      const float iou = (uni > 0.0f) ? (inter / uni) : 0.0f;
      if (iou > 0.5f) s_score[i] = -INFINITY;   // self iou=1 -> suppressed
    }
    kept++;
    __syncthreads();
  }
  __syncthreads();

  if (lane == 0) counts[bl] = kept;
  float* ebase = entries + (size_t)bl * KMAX * 8;
  for (int i = lane; i < kept; i += 64) {
    float* e = ebase + (size_t)i * 8;
    const int ci = s_sel[i];
    e[0] = s_sel_score[i];
    e[1] = fminf(fmaxf(s_box[ci][0], 0.0f), 1.0f);
    e[2] = fminf(fmaxf(s_box[ci][1], 0.0f), 1.0f);
    e[3] = fminf(fmaxf(s_box[ci][2], 0.0f), 1.0f);
    e[4] = fminf(fmaxf(s_box[ci][3], 0.0f), 1.0f);
  }
}

template <int N>
__global__ __launch_bounds__(64) void nms_per_class(
    const int* __restrict__ cand_cls, const float* __restrict__ cand_sc,
    const float4* __restrict__ cand_box, float* __restrict__ entries,
    int* __restrict__ counts) {
  constexpr int ITERS = (N + 63) / 64;
  const int bl = blockIdx.x;
  const int b  = bl / NCLS;
  const int l  = bl % NCLS;
  const int lane = threadIdx.x;
  if (l == 0) { if (lane == 0) counts[bl] = 0; return; }

  __shared__ int   s_idx[NMAX];
  __shared__ float s_score[NMAX];
  __shared__ float s_box[NMAX][4];
  __shared__ int   s_sel[KMAX];
  __shared__ float s_sel_score[KMAX];

  // prefetch coalesced class-id scan into registers (compile-time indices)
  int cv[ITERS];
#pragma unroll
  for (int it = 0; it < ITERS; ++it) {
    const int n = it * 64 + lane;
    cv[it] = (n < N) ? cand_cls[b * N + n] : -1;
  }
  int m = 0;
#pragma unroll
  for (int it = 0; it < ITERS; ++it) {
    const bool cand = (cv[it] == l);
    const unsigned long long mask = __ballot(cand);
    if (cand)
      s_idx[m + __popcll(mask & ((1ull << lane) - 1ull))] = it * 64 + lane;
    m += __popcll(mask);
  }
  __syncthreads();

  nms_body(cand_sc, cand_box, entries, counts, N, b, l, bl, lane, m,
           s_idx, s_score, s_box, s_sel, s_sel_score);
}

__global__ __launch_bounds__(64) void nms_per_class_rt(
    const int* __restrict__ cand_cls, const float* __restrict__ cand_sc,
    const float4* __restrict__ cand_box, float* __restrict__ entries,
    int* __restrict__ counts, int N) {
  const int bl = blockIdx.x;
  const int b  = bl / NCLS;
  const int l  = bl % NCLS;
  const int lane = threadIdx.x;
  if (l == 0) { if (lane == 0) counts[bl] = 0; return; }

  __shared__ int   s_idx[NMAX];
  __shared__ float s_score[NMAX];
  __shared__ float s_box[NMAX][4];
  __shared__ int   s_sel[KMAX];
  __shared__ float s_sel_score[KMAX];

  int m = 0;
  for (int n0 = 0; n0 < N; n0 += 64) {
    const int n = n0 + lane;
    const bool cand = (n < N) && (cand_cls[b * N + n] == l);
    const unsigned long long mask = __ballot(cand);
    if (cand)
      s_idx[m + __popcll(mask & ((1ull << lane) - 1ull))] = n;
    m += __popcll(mask);
  }
  __syncthreads();

  nms_body(cand_sc, cand_box, entries, counts, N, b, l, bl, lane, m,
           s_idx, s_score, s_box, s_sel, s_sel_score);
}

// ---------------------------------------------------------------------------
// K3: one block per batch. Prefix-sum the 81 counts, gather 64-bit keys
// (score desc, flat index asc — low bits ARE the payload), bitonic sort only
// next_pow2(total) slots, emit top-200.
// ---------------------------------------------------------------------------
__global__ __launch_bounds__(1024) void topk_per_batch(
    const float* __restrict__ entries,  // [B*NCLS][KMAX][8]
    const int* __restrict__ counts,     // [B*NCLS]
    float* __restrict__ out, int B) {
  const int b   = blockIdx.x;
  const int tid = threadIdx.x;

  __shared__ int s_cnt[NCLS];
  __shared__ int s_off[NCLS];
  __shared__ int s_total, s_M;
  __shared__ unsigned long long s_key[SORT_CAP];

  if (tid < NCLS) s_cnt[tid] = counts[b * NCLS + tid];
  __syncthreads();
  if (tid == 0) {
    int acc = 0;
    for (int l = 0; l < NCLS; ++l) { s_off[l] = acc; acc += s_cnt[l]; }
    s_total = acc;
    int M = 64;
    while (M < acc) M <<= 1;
    s_M = M;
  }
  __syncthreads();
  const int c = s_total;
  const int M = s_M;     // c <= N <= SORT_CAP guaranteed

  for (int i = tid; i < M; i += 1024) s_key[i] = 0ull;
  __syncthreads();
  for (int j = tid; j < NCLS * KMAX; j += 1024) {
    const int l = j / KMAX, k = j - l * KMAX;
    if (k < s_cnt[l]) {
      const float sc = entries[((size_t)(b * NCLS + l) * KMAX + k) * 8];
      const unsigned sb = __float_as_uint(sc);           // score > 0.7 > 0
      s_key[s_off[l] + k] =
          ((unsigned long long)sb << 32) |
          (unsigned long long)(0xFFFFFFFFu - (unsigned)(l * KMAX + k));
    }
  }
  __syncthreads();

  for (int kk = 2; kk <= M; kk <<= 1) {
    for (int j2 = kk >> 1; j2 > 0; j2 >>= 1) {
      for (int i = tid; i < M; i += 1024) {
        const int ixj = i ^ j2;
        if (ixj > i) {
          const bool up = ((i & kk) == 0);  // descending overall
          const unsigned long long a = s_key[i], bb = s_key[ixj];
          const bool sw = up ? (a < bb) : (a > bb);
          if (sw) { s_key[i] = bb; s_key[ixj] = a; }
        }
      }
      __syncthreads();
    }
  }

  if (tid < KMAX) {
    float sc = 0.0f, lb = 0.0f, b0 = 0.0f, b1 = 0.0f, b2 = 0.0f, b3 = 0.0f;
    if (tid < c) {
      const unsigned long long k = s_key[tid];
      const unsigned fi = 0xFFFFFFFFu - (unsigned)(k & 0xFFFFFFFFull);
      const int l = fi / KMAX, kk2 = fi - l * KMAX;
      const float* e = entries + ((size_t)(b * NCLS + l) * KMAX + kk2) * 8;
      sc = e[0];
      lb = (float)l;
      b0 = e[1]; b1 = e[2]; b2 = e[3]; b3 = e[4];
    }
    float* ob = out + (size_t)b * (KMAX * 4) + (size_t)tid * 4;
    ob[0] = b0; ob[1] = b1; ob[2] = b2; ob[3] = b3;
    const size_t boxes_sz = (size_t)B * KMAX * 4;
    out[boxes_sz + (size_t)b * KMAX + tid] = lb;
    out[boxes_sz + (size_t)B * KMAX + (size_t)b * KMAX + tid] = sc;
  }
}

// ---------------------------------------------------------------------------
extern "C" void kernel_launch(void* const* d_in, const int* in_sizes, int n_in,
                              void* d_out, int out_size, void* d_ws, size_t ws_size,
                              hipStream_t stream) {
  const float* rois   = (const float*)d_in[0];
  const float* deltas = (const float*)d_in[1];
  const float* probs  = (const float*)d_in[2];
  float* out = (float*)d_out;

  const int B = 4;
  const int N = in_sizes[0] / (B * 4);   // 1500
  const int BN = B * N;

  char* ws = (char*)d_ws;
  int*    counts   = (int*)ws;
  float*  entries  = (float*)(ws + 4096);
  int*    cand_cls = (int*)(ws + 2077696);
  float*  cand_sc  = (float*)(ws + 2077696 + 24064);
  float4* cand_box = (float4*)(ws + 2077696 + 24064 + 24064);

  hipLaunchKernelGGL(row_scan, dim3((BN + 63) / 64), dim3(64), 0, stream,
                     rois, deltas, probs, cand_cls, cand_sc, cand_box, BN);
  if (N == 1500) {
    hipLaunchKernelGGL((nms_per_class<1500>), dim3(B * NCLS), dim3(64), 0,
                       stream, cand_cls, cand_sc, cand_box, entries, counts);
  } else {
    hipLaunchKernelGGL(nms_per_class_rt, dim3(B * NCLS), dim3(64), 0, stream,
                       cand_cls, cand_sc, cand_box, entries, counts, N);
  }
  hipLaunchKernelGGL(topk_per_batch, dim3(B), dim3(1024), 0, stream,
                     entries, counts, out, B);
}